// Round 10
// baseline (211.458 us; speedup 1.0000x reference)
//
#include <hip/hip_runtime.h>

#define NPTS 8192
#define KNN 8
// phase A (subset) geometry
#define NSUB 4096
#define ASLICE 256
#define NSLICE_A (NSUB / ASLICE)  // 16
// phase C (full gated scan) geometry
#define CSLICE 512
#define NSLICE_C (NPTS / CSLICE)  // 16

typedef short bf16x8 __attribute__((ext_vector_type(8)));
typedef float f32x4 __attribute__((ext_vector_type(4)));

// bf16 round-to-nearest-even split helpers.
__device__ __forceinline__ unsigned short f2bf(float x) {
  unsigned int u = __float_as_uint(x);
  return (unsigned short)((u + 0x7FFF + ((u >> 16) & 1)) >> 16);
}
__device__ __forceinline__ float bf2f(unsigned short s) {
  return __uint_as_float(((unsigned int)s) << 16);
}

// Exact distance, replicating numpy rounding. Same bits every use.
__device__ __forceinline__ float dist_exact(float qx, float qy, float qz,
                                            float q2, float px, float py,
                                            float pz, float p2) {
  float dot = __fmaf_rn(qz, pz, __fmaf_rn(qy, py, __fmul_rn(qx, px)));
  float t1 = __fadd_rn(q2, p2);
  return __fadd_rn(t1, __fmul_rn(-2.0f, dot));
}

__device__ __forceinline__ float norm2_exact(float x, float y, float z) {
  return __fadd_rn(__fadd_rn(__fmul_rn(x, x), __fmul_rn(y, y)),
                   __fmul_rn(z, z));
}

// Monotone (d, idx) -> f64 key (verified R8): lex (d_bits, idx) order ==
// IEEE f64 order; ascending keys == jax.lax.top_k order (stable ties).
__device__ __forceinline__ double pack_key(float d, int idx) {
  unsigned int ub = __float_as_uint(d);
  ub ^= (((unsigned int)((int)ub >> 31)) | 0x80000000u);
  unsigned int lo = (ub << 13) | (unsigned int)idx;
  unsigned int hi = 0x3ff00000u | (ub >> 19);
  return __hiloint2double((int)hi, (int)lo);
}

#define KEY_DECL                                                            \
  const double KINF = __longlong_as_double(0x7ff0000000000000LL);           \
  double k0 = KINF, k1 = KINF, k2 = KINF, k3 = KINF, k4 = KINF, k5 = KINF,  \
         k6 = KINF, k7 = KINF;

// Parallel sorted-insert (med3 identity, verified R9): depth 2, 15 ops.
#define KEY_INSERT(key)                                                     \
  {                                                                         \
    double x = (key);                                                       \
    double m0 = fmax(x, k0), m1 = fmax(x, k1), m2 = fmax(x, k2);            \
    double m3 = fmax(x, k3), m4 = fmax(x, k4), m5 = fmax(x, k5);            \
    double m6 = fmax(x, k6);                                                \
    k7 = fmin(m6, k7);                                                      \
    k6 = fmin(m5, k6);                                                      \
    k5 = fmin(m4, k5);                                                      \
    k4 = fmin(m3, k4);                                                      \
    k3 = fmin(m2, k3);                                                      \
    k2 = fmin(m1, k2);                                                      \
    k1 = fmin(m0, k1);                                                      \
    k0 = fmin(x, k0);                                                       \
  }

// f32 value-only parallel sorted-insert (same med3 identity), 15 f32 ops.
#define VAL_DECL                                                            \
  float v0 = 3.4e38f, v1 = 3.4e38f, v2 = 3.4e38f, v3 = 3.4e38f,            \
        v4 = 3.4e38f, v5 = 3.4e38f, v6 = 3.4e38f, v7 = 3.4e38f;
#define VAL_INSERT(val)                                                     \
  {                                                                         \
    float x = (val);                                                        \
    float m0 = fmaxf(x, v0), m1 = fmaxf(x, v1), m2 = fmaxf(x, v2);          \
    float m3 = fmaxf(x, v3), m4 = fmaxf(x, v4), m5 = fmaxf(x, v5);          \
    float m6 = fmaxf(x, v6);                                                \
    v7 = fminf(m6, v7);                                                     \
    v6 = fminf(m5, v6);                                                     \
    v5 = fminf(m4, v5);                                                     \
    v4 = fminf(m3, v4);                                                     \
    v3 = fminf(m2, v3);                                                     \
    v2 = fminf(m1, v2);                                                     \
    v1 = fminf(m0, v1);                                                     \
    v0 = fminf(x, v0);                                                      \
  }

// ---------------------------------------------------------------------------
// KNN A: subset scan. Per (query, slice of 256 from candidates [0,NSUB)),
// keep top-8 distance VALUES (f32, no indices). part_v[q*128 + slice*8+s].
// The 8th-smallest over the subset is a VALID upper bound on the true
// 8th-smallest (multiset argument) -> used as capture threshold in phase C.
// ---------------------------------------------------------------------------
__global__ __launch_bounds__(256) void knn_subset_kernel(
    const float* __restrict__ pts, float* __restrict__ part_v) {
  __shared__ float4 sp[ASLICE];
  const int t = threadIdx.x;
  const int q = blockIdx.x * 256 + t;
  const int jbase = blockIdx.y * ASLICE;
  if (t < ASLICE) {
    float x = pts[(jbase + t) * 3 + 0];
    float y = pts[(jbase + t) * 3 + 1];
    float z = pts[(jbase + t) * 3 + 2];
    sp[t] = make_float4(x, y, z, norm2_exact(x, y, z));
  }
  __syncthreads();
  const float qx = pts[q * 3 + 0], qy = pts[q * 3 + 1], qz = pts[q * 3 + 2];
  const float q2 = norm2_exact(qx, qy, qz);
  VAL_DECL;
  for (int p = 0; p < ASLICE; p += 4) {
    float4 c0 = sp[p + 0];
    float4 c1 = sp[p + 1];
    float4 c2 = sp[p + 2];
    float4 c3 = sp[p + 3];
    VAL_INSERT(dist_exact(qx, qy, qz, q2, c0.x, c0.y, c0.z, c0.w));
    VAL_INSERT(dist_exact(qx, qy, qz, q2, c1.x, c1.y, c1.z, c1.w));
    VAL_INSERT(dist_exact(qx, qy, qz, q2, c2.x, c2.y, c2.z, c2.w));
    VAL_INSERT(dist_exact(qx, qy, qz, q2, c3.x, c3.y, c3.z, c3.w));
  }
  float* o = &part_v[(size_t)q * (NSLICE_A * KNN) + blockIdx.y * 8];
  o[0] = v0; o[1] = v1; o[2] = v2; o[3] = v3;
  o[4] = v4; o[5] = v5; o[6] = v6; o[7] = v7;
}

// ---------------------------------------------------------------------------
// KNN B: tau[q] = 8th-smallest over the 128 subset values.
// ---------------------------------------------------------------------------
__global__ __launch_bounds__(256) void knn_tau_kernel(
    const float* __restrict__ part_v, float* __restrict__ tau) {
  const int q = blockIdx.x * 256 + threadIdx.x;
  const float4* v4p = (const float4*)&part_v[(size_t)q * 128];
  VAL_DECL;
#pragma unroll 8
  for (int u = 0; u < 32; ++u) {
    float4 v = v4p[u];
    VAL_INSERT(v.x);
    VAL_INSERT(v.y);
    VAL_INSERT(v.z);
    VAL_INSERT(v.w);
  }
  tau[q] = v7;
}

// ---------------------------------------------------------------------------
// KNN C: full scan; only candidates with d <= tau[q] enter the f64-key
// top-8 bubble (rare: ~16 survivors/query -> ~12% of wave-iters take the
// branch). Per-slice capture capacity is automatic: any key displaced from
// a slice's top-8 is beaten by 8 in-slice keys, so it cannot be global
// top-8. Output part_k[q*128 + slice*8 + s].
// ---------------------------------------------------------------------------
__global__ __launch_bounds__(256) void knn_scan_tau_kernel(
    const float* __restrict__ pts, const float* __restrict__ tau,
    double* __restrict__ part_k) {
  __shared__ float4 sp[CSLICE];
  const int t = threadIdx.x;
  const int q = blockIdx.x * 256 + t;
  const int jbase = blockIdx.y * CSLICE;
  for (int p = t; p < CSLICE; p += 256) {
    float x = pts[(jbase + p) * 3 + 0];
    float y = pts[(jbase + p) * 3 + 1];
    float z = pts[(jbase + p) * 3 + 2];
    sp[p] = make_float4(x, y, z, norm2_exact(x, y, z));
  }
  __syncthreads();
  const float qx = pts[q * 3 + 0], qy = pts[q * 3 + 1], qz = pts[q * 3 + 2];
  const float q2 = norm2_exact(qx, qy, qz);
  const float tq = tau[q];
  KEY_DECL;
  for (int p = 0; p < CSLICE; p += 4) {
    float4 c0 = sp[p + 0];
    float4 c1 = sp[p + 1];
    float4 c2 = sp[p + 2];
    float4 c3 = sp[p + 3];
    float e0 = dist_exact(qx, qy, qz, q2, c0.x, c0.y, c0.z, c0.w);
    float e1 = dist_exact(qx, qy, qz, q2, c1.x, c1.y, c1.z, c1.w);
    float e2 = dist_exact(qx, qy, qz, q2, c2.x, c2.y, c2.z, c2.w);
    float e3 = dist_exact(qx, qy, qz, q2, c3.x, c3.y, c3.z, c3.w);
    if (e0 <= tq) KEY_INSERT(pack_key(e0, jbase + p + 0));
    if (e1 <= tq) KEY_INSERT(pack_key(e1, jbase + p + 1));
    if (e2 <= tq) KEY_INSERT(pack_key(e2, jbase + p + 2));
    if (e3 <= tq) KEY_INSERT(pack_key(e3, jbase + p + 3));
  }
  double* o = &part_k[(size_t)q * (NSLICE_C * KNN) + blockIdx.y * 8];
  o[0] = k0; o[1] = k1; o[2] = k2; o[3] = k3;
  o[4] = k4; o[5] = k5; o[6] = k6; o[7] = k7;
}

// ---------------------------------------------------------------------------
// KNN D: merge 128 keys/query -> nbr (idx = low 13 bits).
// ---------------------------------------------------------------------------
__global__ __launch_bounds__(64) void knn_merge2_kernel(
    const double* __restrict__ part_k, int* __restrict__ nbr) {
  const int q = blockIdx.x * 64 + threadIdx.x;
  const double* kv = &part_k[(size_t)q * (NSLICE_C * KNN)];
  KEY_DECL;
#pragma unroll 8
  for (int u = 0; u < NSLICE_C * KNN; u += 4) {
    double a = kv[u + 0];
    double b = kv[u + 1];
    double c = kv[u + 2];
    double d = kv[u + 3];
    KEY_INSERT(a);
    KEY_INSERT(b);
    KEY_INSERT(c);
    KEY_INSERT(d);
  }
  nbr[q * KNN + 0] = __double2loint(k0) & 0x1fff;
  nbr[q * KNN + 1] = __double2loint(k1) & 0x1fff;
  nbr[q * KNN + 2] = __double2loint(k2) & 0x1fff;
  nbr[q * KNN + 3] = __double2loint(k3) & 0x1fff;
  nbr[q * KNN + 4] = __double2loint(k4) & 0x1fff;
  nbr[q * KNN + 5] = __double2loint(k5) & 0x1fff;
  nbr[q * KNN + 6] = __double2loint(k6) & 0x1fff;
  nbr[q * KNN + 7] = __double2loint(k7) & 0x1fff;
}

// ---------------------------------------------------------------------------
// Fused EdgeConv1: H1 tile in LDS, GEMM W2, max8, +b2, relu -> y (8192x128).
// ---------------------------------------------------------------------------
__global__ __launch_bounds__(256) void gemm1_fused_kernel(
    const float* __restrict__ pts, const int* __restrict__ nbr,
    const float* __restrict__ W1, const float* __restrict__ b1,
    const float* __restrict__ W2, const float* __restrict__ b2,
    float* __restrict__ y) {
  __shared__ float es[64][6];
  __shared__ float W1s[6][64];
  __shared__ float b1s[64];
  __shared__ float As[64][64];
  __shared__ float Bs[64][64];
  const int t = threadIdx.x;
  const int rowBase = blockIdx.y * 64;
  const int colBase = blockIdx.x * 64;

  for (int idx = t; idx < 384; idx += 256) W1s[idx >> 6][idx & 63] = W1[idx];
  if (t < 64) b1s[t] = b1[t];
  {
    int cq = t & 15, kr = t >> 4;
#pragma unroll
    for (int it = 0; it < 4; ++it) {
      int k = it * 16 + kr;
      *(float4*)&Bs[k][cq * 4] =
          *(const float4*)&W2[(size_t)k * 128 + colBase + cq * 4];
    }
  }
  if (t < 64) {
    int e = rowBase + t;
    int i = e >> 3;
    int j = nbr[e];
    float xi0 = pts[i * 3], xi1 = pts[i * 3 + 1], xi2 = pts[i * 3 + 2];
    es[t][0] = xi0;
    es[t][1] = xi1;
    es[t][2] = xi2;
    es[t][3] = pts[j * 3] - xi0;
    es[t][4] = pts[j * 3 + 1] - xi1;
    es[t][5] = pts[j * 3 + 2] - xi2;
  }
  __syncthreads();

  {
    const int e = t & 63, k0 = (t >> 6) * 16;
    const float f0 = es[e][0], f1 = es[e][1], f2 = es[e][2];
    const float f3 = es[e][3], f4 = es[e][4], f5 = es[e][5];
#pragma unroll
    for (int k = 0; k < 16; ++k) {
      int c = k0 + k;
      float v = b1s[c];
      v = fmaf(f0, W1s[0][c], v);
      v = fmaf(f1, W1s[1][c], v);
      v = fmaf(f2, W1s[2][c], v);
      v = fmaf(f3, W1s[3][c], v);
      v = fmaf(f4, W1s[4][c], v);
      v = fmaf(f5, W1s[5][c], v);
      As[c][e] = fmaxf(v, 0.0f);
    }
  }
  __syncthreads();

  const int tx = t & 15, ty = t >> 4;
  float acc[4][4] = {};
#pragma unroll 8
  for (int k = 0; k < 64; ++k) {
    float4 a = *(const float4*)&As[k][ty * 4];
    float4 b = *(const float4*)&Bs[k][tx * 4];
    const float ar[4] = {a.x, a.y, a.z, a.w};
    const float br[4] = {b.x, b.y, b.z, b.w};
#pragma unroll
    for (int i = 0; i < 4; ++i)
#pragma unroll
      for (int jj = 0; jj < 4; ++jj)
        acc[i][jj] = fmaf(ar[i], br[jj], acc[i][jj]);
  }
  __syncthreads();

  float* Mx = &As[0][0];
#pragma unroll
  for (int jj = 0; jj < 4; ++jj) {
    float m =
        fmaxf(fmaxf(acc[0][jj], acc[1][jj]), fmaxf(acc[2][jj], acc[3][jj]));
    Mx[ty * 64 + tx * 4 + jj] = m;
  }
  __syncthreads();
  if (t < 128) {
    int p = t >> 4, cq = t & 15;
    int c = cq * 4;
    float4 o;
    float* oa = (float*)&o;
#pragma unroll
    for (int jj = 0; jj < 4; ++jj) {
      float v = fmaxf(Mx[(2 * p) * 64 + c + jj], Mx[(2 * p + 1) * 64 + c + jj]);
      v += b2[colBase + c + jj];
      oa[jj] = fmaxf(v, 0.0f);
    }
    *(float4*)&y[(size_t)(blockIdx.y * 8 + p) * 128 + colBase + c] = o;
  }
}

// Build Wcat (128 x 256) from W3 (256 x 128).
__global__ __launch_bounds__(256) void build_wcat_kernel(
    const float* __restrict__ W3, float* __restrict__ Wcat) {
  const int id = blockIdx.x * 256 + threadIdx.x;
  const int k = id >> 8, c = id & 255;
  Wcat[id] = (c < 128) ? W3[k * 128 + c] : W3[(128 + k) * 128 + (c - 128)];
}

// Split W4 (128x256 fp32) into transposed bf16 hi/lo: W4ht/W4lt[col*128+k].
__global__ __launch_bounds__(256) void w4split_kernel(
    const float* __restrict__ W4, unsigned short* __restrict__ W4ht,
    unsigned short* __restrict__ W4lt) {
  const int id = blockIdx.x * 256 + threadIdx.x;  // 32768
  const int k = id >> 8, c = id & 255;
  float v = W4[k * 256 + c];
  unsigned short hi = f2bf(v);
  unsigned short lo = f2bf(v - bf2f(hi));
  W4ht[c * 128 + k] = hi;
  W4lt[c * 128 + k] = lo;
}

// ---------------------------------------------------------------------------
// AC = y @ Wcat (+b3 on cols<128). 64x64 GEMM (8192x128x256).
// ---------------------------------------------------------------------------
__global__ __launch_bounds__(256) void gemm_ac_kernel(
    const float* __restrict__ A, const float* __restrict__ B,
    const float* __restrict__ bias, float* __restrict__ out) {
  __shared__ float As[64][64];
  __shared__ float Bs[64][64];
  const int t = threadIdx.x;
  const int tx = t & 15, ty = t >> 4;
  const int rowBase = blockIdx.y * 64;
  const int colBase = blockIdx.x * 64;
  const float4* A4 = (const float4*)A;
  float acc[4][4] = {};
  const int K = 128, Nglob = 256;

  for (int k0 = 0; k0 < K; k0 += 64) {
#pragma unroll
    for (int it = 0; it < 4; ++it) {
      int idx = it * 256 + t;
      int row = idx & 63, kq = idx >> 6;
      float4 av = A4[(size_t)(rowBase + row) * (K >> 2) + (k0 >> 2) + kq];
      As[kq * 4 + 0][row] = av.x;
      As[kq * 4 + 1][row] = av.y;
      As[kq * 4 + 2][row] = av.z;
      As[kq * 4 + 3][row] = av.w;
    }
#pragma unroll
    for (int it = 0; it < 4; ++it) {
      int idx = it * 256 + t;
      int cq = idx & 15, kr = idx >> 4;
      float4 bv =
          *(const float4*)&B[(size_t)(k0 + kr) * Nglob + colBase + cq * 4];
      *(float4*)&Bs[kr][cq * 4] = bv;
    }
    __syncthreads();
#pragma unroll 8
    for (int k = 0; k < 64; ++k) {
      float4 a = *(const float4*)&As[k][ty * 4];
      float4 b = *(const float4*)&Bs[k][tx * 4];
      const float ar[4] = {a.x, a.y, a.z, a.w};
      const float br[4] = {b.x, b.y, b.z, b.w};
#pragma unroll
      for (int i = 0; i < 4; ++i)
#pragma unroll
        for (int jj = 0; jj < 4; ++jj)
          acc[i][jj] = fmaf(ar[i], br[jj], acc[i][jj]);
    }
    __syncthreads();
  }

#pragma unroll
  for (int i = 0; i < 4; ++i) {
    float4 o;
    float* oa = (float*)&o;
#pragma unroll
    for (int jj = 0; jj < 4; ++jj) {
      float v = acc[i][jj];
      int cg = colBase + tx * 4 + jj;
      if (cg < 128) v += bias[cg];
      oa[jj] = v;
    }
    *(float4*)&out[(size_t)(rowBase + ty * 4 + i) * Nglob + colBase + tx * 4] =
        o;
  }
}

// ---------------------------------------------------------------------------
// MFMA EdgeConv2 second layer (split-bf16), verified R7/R8:
// D = Hh*Wh + Hh*Wl + Hl*Wh in fp32 MFMA acc; in-register segmax + b4.
// ---------------------------------------------------------------------------
__global__ __launch_bounds__(256) void gemm2_mfma_kernel(
    const float* __restrict__ AC, const int* __restrict__ nbr,
    const unsigned short* __restrict__ W4ht,
    const unsigned short* __restrict__ W4lt, const float* __restrict__ b4,
    float* __restrict__ out) {
  __shared__ unsigned short H2h[128 * 40];
  __shared__ unsigned short H2l[128 * 40];
  __shared__ unsigned short Wth[128 * 40];
  __shared__ unsigned short Wtl[128 * 40];
  const int t = threadIdx.x;
  const int rowBase = blockIdx.y * 128;
  const int colBase = blockIdx.x * 128;
  const int eloc = t >> 1, hh = t & 1;
  const int kb = hh * 16;
  const int edge = rowBase + eloc;
  const int ip = edge >> 3;
  const int jp = nbr[edge];
  const float* ai_p = AC + (size_t)ip * 256;
  const float* ci_p = ai_p + 128;
  const float* cj_p = AC + (size_t)jp * 256 + 128;
  const int lane = t & 63;
  const int w = t >> 6;
  const int q = lane >> 4;
  const int nidx = lane & 15;

  f32x4 acc[2][8];
#pragma unroll
  for (int mt = 0; mt < 2; ++mt)
#pragma unroll
    for (int nt = 0; nt < 8; ++nt) acc[mt][nt] = (f32x4){0.f, 0.f, 0.f, 0.f};

  for (int p = 0; p < 4; ++p) {
    const int k0 = p * 32;
    {
      float h2[16];
      const float4* a4 = (const float4*)(ai_p + k0 + kb);
      const float4* c4 = (const float4*)(ci_p + k0 + kb);
      const float4* d4 = (const float4*)(cj_p + k0 + kb);
#pragma unroll
      for (int u = 0; u < 4; ++u) {
        float4 a = a4[u], c = c4[u], d = d4[u];
        h2[u * 4 + 0] = fmaxf(a.x + d.x - c.x, 0.f);
        h2[u * 4 + 1] = fmaxf(a.y + d.y - c.y, 0.f);
        h2[u * 4 + 2] = fmaxf(a.z + d.z - c.z, 0.f);
        h2[u * 4 + 3] = fmaxf(a.w + d.w - c.w, 0.f);
      }
      unsigned int hp[8], lp[8];
#pragma unroll
      for (int u = 0; u < 8; ++u) {
        unsigned short h0 = f2bf(h2[2 * u]), h1 = f2bf(h2[2 * u + 1]);
        hp[u] = (unsigned int)h0 | ((unsigned int)h1 << 16);
        unsigned short l0 = f2bf(h2[2 * u] - bf2f(h0));
        unsigned short l1 = f2bf(h2[2 * u + 1] - bf2f(h1));
        lp[u] = (unsigned int)l0 | ((unsigned int)l1 << 16);
      }
      *(uint4*)&H2h[eloc * 40 + kb] = make_uint4(hp[0], hp[1], hp[2], hp[3]);
      *(uint4*)&H2h[eloc * 40 + kb + 8] =
          make_uint4(hp[4], hp[5], hp[6], hp[7]);
      *(uint4*)&H2l[eloc * 40 + kb] = make_uint4(lp[0], lp[1], lp[2], lp[3]);
      *(uint4*)&H2l[eloc * 40 + kb + 8] =
          make_uint4(lp[4], lp[5], lp[6], lp[7]);
    }
    {
      const size_t src = (size_t)(colBase + eloc) * 128 + k0 + kb;
      *(uint4*)&Wth[eloc * 40 + kb] = *(const uint4*)&W4ht[src];
      *(uint4*)&Wth[eloc * 40 + kb + 8] = *(const uint4*)&W4ht[src + 8];
      *(uint4*)&Wtl[eloc * 40 + kb] = *(const uint4*)&W4lt[src];
      *(uint4*)&Wtl[eloc * 40 + kb + 8] = *(const uint4*)&W4lt[src + 8];
    }
    __syncthreads();
    bf16x8 ah[2], al[2];
#pragma unroll
    for (int mt = 0; mt < 2; ++mt) {
      int row = w * 32 + mt * 16 + nidx;
      ah[mt] = *(const bf16x8*)&H2h[row * 40 + q * 8];
      al[mt] = *(const bf16x8*)&H2l[row * 40 + q * 8];
    }
#pragma unroll
    for (int nt = 0; nt < 8; ++nt) {
      int col = nt * 16 + nidx;
      bf16x8 bh = *(const bf16x8*)&Wth[col * 40 + q * 8];
      bf16x8 bl = *(const bf16x8*)&Wtl[col * 40 + q * 8];
#pragma unroll
      for (int mt = 0; mt < 2; ++mt) {
        acc[mt][nt] = __builtin_amdgcn_mfma_f32_16x16x32_bf16(
            ah[mt], bh, acc[mt][nt], 0, 0, 0);
        acc[mt][nt] = __builtin_amdgcn_mfma_f32_16x16x32_bf16(
            ah[mt], bl, acc[mt][nt], 0, 0, 0);
        acc[mt][nt] = __builtin_amdgcn_mfma_f32_16x16x32_bf16(
            al[mt], bh, acc[mt][nt], 0, 0, 0);
      }
    }
    __syncthreads();
  }

#pragma unroll
  for (int mt = 0; mt < 2; ++mt) {
    const int ebase = rowBase + w * 32 + mt * 16;
    const int pt0 = ebase >> 3;
#pragma unroll
    for (int nt = 0; nt < 8; ++nt) {
      f32x4 a = acc[mt][nt];
      float m = fmaxf(fmaxf(a[0], a[1]), fmaxf(a[2], a[3]));
      float o = fmaxf(m, __shfl_xor(m, 16, 64));
      int cg = colBase + nt * 16 + nidx;
      if (q == 0) {
        out[(size_t)pt0 * 256 + cg] = o + b4[cg];
      } else if (q == 2) {
        out[(size_t)(pt0 + 1) * 256 + cg] = o + b4[cg];
      }
    }
  }
}

extern "C" void kernel_launch(void* const* d_in, const int* in_sizes, int n_in,
                              void* d_out, int out_size, void* d_ws,
                              size_t ws_size, hipStream_t stream) {
  const float* pts = (const float*)d_in[0];
  const float* W1 = (const float*)d_in[1];
  const float* b1 = (const float*)d_in[2];
  const float* W2 = (const float*)d_in[3];
  const float* b2 = (const float*)d_in[4];
  const float* W3 = (const float*)d_in[5];
  const float* b3 = (const float*)d_in[6];
  const float* W4 = (const float*)d_in[7];
  const float* b4 = (const float*)d_in[8];
  float* out = (float*)d_out;

  float* w = (float*)d_ws;
  float* part_v = w;                           // 1048576 f
  float* tau = w + 1048576;                    // 8192 f
  double* part_k = (double*)(w + 1056768);     // 8192*128 dbl = 2097152 f
  int* nbr = (int*)(w + 3153920);              // 65536 i
  float* y = w + 3219456;                      // 1048576 f
  float* Wcat = w + 4268032;                   // 32768 f
  float* AC = w + 4300800;                     // 2097152 f
  unsigned short* W4ht = (unsigned short*)(w + 6397952);  // 32768 us
  unsigned short* W4lt = (unsigned short*)(w + 6414336);  // 32768 us

  // 1. KNN: subset vals -> tau (upper bound) -> gated exact capture -> merge
  knn_subset_kernel<<<dim3(32, NSLICE_A), 256, 0, stream>>>(pts, part_v);
  knn_tau_kernel<<<32, 256, 0, stream>>>(part_v, tau);
  knn_scan_tau_kernel<<<dim3(32, NSLICE_C), 256, 0, stream>>>(pts, tau,
                                                              part_k);
  knn_merge2_kernel<<<128, 64, 0, stream>>>(part_k, nbr);

  // 2. EdgeConv1 (fused H1 + GEMM + max8 + b2 + relu)
  gemm1_fused_kernel<<<dim3(2, 1024), 256, 0, stream>>>(pts, nbr, W1, b1, W2,
                                                        b2, y);

  // 3. EdgeConv2: AC = y@Wcat (+b3), then MFMA H2+GEMM+max8+b4 -> out
  build_wcat_kernel<<<128, 256, 0, stream>>>(W3, Wcat);
  w4split_kernel<<<128, 256, 0, stream>>>(W4, W4ht, W4lt);
  gemm_ac_kernel<<<dim3(4, 128), 256, 0, stream>>>(y, Wcat, b3, AC);
  gemm2_mfma_kernel<<<dim3(2, 512), 256, 0, stream>>>(AC, nbr, W4ht, W4lt, b4,
                                                      out);
}

// Round 12
// 201.440 us; speedup vs baseline: 1.0497x; 1.0497x over previous
//
#include <hip/hip_runtime.h>

#define NPTS 8192
#define KNN 8
// phase A (subset) geometry
#define NSUB 4096
#define ASLICE 256
#define NSLICE_A (NSUB / ASLICE)  // 16
// phase C (full gated scan) geometry
#define CSLICE 512
#define NSLICE_C (NPTS / CSLICE)  // 16

typedef short bf16x8 __attribute__((ext_vector_type(8)));
typedef float f32x4 __attribute__((ext_vector_type(4)));

// bf16 round-to-nearest-even split helpers.
__device__ __forceinline__ unsigned short f2bf(float x) {
  unsigned int u = __float_as_uint(x);
  return (unsigned short)((u + 0x7FFF + ((u >> 16) & 1)) >> 16);
}
__device__ __forceinline__ float bf2f(unsigned short s) {
  return __uint_as_float(((unsigned int)s) << 16);
}

// Exact distance, replicating numpy rounding. Same bits every use.
__device__ __forceinline__ float dist_exact(float qx, float qy, float qz,
                                            float q2, float px, float py,
                                            float pz, float p2) {
  float dot = __fmaf_rn(qz, pz, __fmaf_rn(qy, py, __fmul_rn(qx, px)));
  float t1 = __fadd_rn(q2, p2);
  return __fadd_rn(t1, __fmul_rn(-2.0f, dot));
}

__device__ __forceinline__ float norm2_exact(float x, float y, float z) {
  return __fadd_rn(__fadd_rn(__fmul_rn(x, x), __fmul_rn(y, y)),
                   __fmul_rn(z, z));
}

// Monotone (d, idx) -> f64 key (verified R8): lex (d_bits, idx) order ==
// IEEE f64 order; ascending keys == jax.lax.top_k order (stable ties).
__device__ __forceinline__ double pack_key(float d, int idx) {
  unsigned int ub = __float_as_uint(d);
  ub ^= (((unsigned int)((int)ub >> 31)) | 0x80000000u);
  unsigned int lo = (ub << 13) | (unsigned int)idx;
  unsigned int hi = 0x3ff00000u | (ub >> 19);
  return __hiloint2double((int)hi, (int)lo);
}

#define KEY_DECL                                                            \
  const double KINF = __longlong_as_double(0x7ff0000000000000LL);           \
  double k0 = KINF, k1 = KINF, k2 = KINF, k3 = KINF, k4 = KINF, k5 = KINF,  \
         k6 = KINF, k7 = KINF;

// Parallel sorted-insert (med3 identity, verified R9): depth 2, 15 ops.
// Inserting +inf is the identity. NOTE: all macro-internal temporaries are
// underscore-prefixed -- R11 failed because a caller temp named `x` was
// captured by the macro's own `double x = (key)` (self-init UB).
#define KEY_INSERT(key)                                                     \
  {                                                                         \
    const double _x = (key);                                                \
    const double _m0 = fmax(_x, k0), _m1 = fmax(_x, k1);                    \
    const double _m2 = fmax(_x, k2), _m3 = fmax(_x, k3);                    \
    const double _m4 = fmax(_x, k4), _m5 = fmax(_x, k5);                    \
    const double _m6 = fmax(_x, k6);                                        \
    k7 = fmin(_m6, k7);                                                     \
    k6 = fmin(_m5, k6);                                                     \
    k5 = fmin(_m4, k5);                                                     \
    k4 = fmin(_m3, k4);                                                     \
    k3 = fmin(_m2, k3);                                                     \
    k2 = fmin(_m1, k2);                                                     \
    k1 = fmin(_m0, k1);                                                     \
    k0 = fmin(_x, k0);                                                      \
  }

// f32 value-only parallel sorted-insert (same med3 identity), 15 f32 ops.
#define VAL_DECL                                                            \
  float v0 = 3.4e38f, v1 = 3.4e38f, v2 = 3.4e38f, v3 = 3.4e38f,            \
        v4 = 3.4e38f, v5 = 3.4e38f, v6 = 3.4e38f, v7 = 3.4e38f;
#define VAL_INSERT(val)                                                     \
  {                                                                         \
    const float _x = (val);                                                 \
    const float _m0 = fmaxf(_x, v0), _m1 = fmaxf(_x, v1);                   \
    const float _m2 = fmaxf(_x, v2), _m3 = fmaxf(_x, v3);                   \
    const float _m4 = fmaxf(_x, v4), _m5 = fmaxf(_x, v5);                   \
    const float _m6 = fmaxf(_x, v6);                                        \
    v7 = fminf(_m6, v7);                                                    \
    v6 = fminf(_m5, v6);                                                    \
    v5 = fminf(_m4, v5);                                                    \
    v4 = fminf(_m3, v4);                                                    \
    v3 = fminf(_m2, v3);                                                    \
    v2 = fminf(_m1, v2);                                                    \
    v1 = fminf(_m0, v1);                                                    \
    v0 = fminf(_x, v0);                                                     \
  }

// ---------------------------------------------------------------------------
// KNN A: subset scan (candidates [0,NSUB)), top-8 f32 VALUES per slice.
// 8th-smallest over a subset is a valid upper bound on the true 8th.
// ---------------------------------------------------------------------------
__global__ __launch_bounds__(256) void knn_subset_kernel(
    const float* __restrict__ pts, float* __restrict__ part_v) {
  __shared__ float4 sp[ASLICE];
  const int t = threadIdx.x;
  const int q = blockIdx.x * 256 + t;
  const int jbase = blockIdx.y * ASLICE;
  if (t < ASLICE) {
    float x = pts[(jbase + t) * 3 + 0];
    float y = pts[(jbase + t) * 3 + 1];
    float z = pts[(jbase + t) * 3 + 2];
    sp[t] = make_float4(x, y, z, norm2_exact(x, y, z));
  }
  __syncthreads();
  const float qx = pts[q * 3 + 0], qy = pts[q * 3 + 1], qz = pts[q * 3 + 2];
  const float q2 = norm2_exact(qx, qy, qz);
  VAL_DECL;
  for (int p = 0; p < ASLICE; p += 4) {
    float4 c0 = sp[p + 0];
    float4 c1 = sp[p + 1];
    float4 c2 = sp[p + 2];
    float4 c3 = sp[p + 3];
    VAL_INSERT(dist_exact(qx, qy, qz, q2, c0.x, c0.y, c0.z, c0.w));
    VAL_INSERT(dist_exact(qx, qy, qz, q2, c1.x, c1.y, c1.z, c1.w));
    VAL_INSERT(dist_exact(qx, qy, qz, q2, c2.x, c2.y, c2.z, c2.w));
    VAL_INSERT(dist_exact(qx, qy, qz, q2, c3.x, c3.y, c3.z, c3.w));
  }
  float* o = &part_v[(size_t)q * (NSLICE_A * KNN) + blockIdx.y * 8];
  o[0] = v0; o[1] = v1; o[2] = v2; o[3] = v3;
  o[4] = v4; o[5] = v5; o[6] = v6; o[7] = v7;
}

// ---------------------------------------------------------------------------
// KNN B: tau[q] = 8th-smallest over the 128 subset values.
// ---------------------------------------------------------------------------
__global__ __launch_bounds__(256) void knn_tau_kernel(
    const float* __restrict__ part_v, float* __restrict__ tau) {
  const int q = blockIdx.x * 256 + threadIdx.x;
  const float4* v4p = (const float4*)&part_v[(size_t)q * 128];
  VAL_DECL;
#pragma unroll 8
  for (int u = 0; u < 32; ++u) {
    float4 v = v4p[u];
    VAL_INSERT(v.x);
    VAL_INSERT(v.y);
    VAL_INSERT(v.z);
    VAL_INSERT(v.w);
  }
  tau[q] = v7;
}

// ---------------------------------------------------------------------------
// KNN C: full scan with WAVE-UNIFORM ballot gates. __ballot -> SGPR ->
// s_cbranch skips the f64 bubble when no lane hits (~88% of groups).
// In-gate, lanes without a hit insert +inf (identity) -- no per-lane branch.
// ---------------------------------------------------------------------------
__global__ __launch_bounds__(256) void knn_scan_tau_kernel(
    const float* __restrict__ pts, const float* __restrict__ tau,
    double* __restrict__ part_k) {
  __shared__ float4 sp[CSLICE];
  const int t = threadIdx.x;
  const int q = blockIdx.x * 256 + t;
  const int jbase = blockIdx.y * CSLICE;
  for (int p = t; p < CSLICE; p += 256) {
    float x = pts[(jbase + p) * 3 + 0];
    float y = pts[(jbase + p) * 3 + 1];
    float z = pts[(jbase + p) * 3 + 2];
    sp[p] = make_float4(x, y, z, norm2_exact(x, y, z));
  }
  __syncthreads();
  const float qx = pts[q * 3 + 0], qy = pts[q * 3 + 1], qz = pts[q * 3 + 2];
  const float q2 = norm2_exact(qx, qy, qz);
  const float tq = tau[q];
  KEY_DECL;
  for (int p = 0; p < CSLICE; p += 4) {
    float4 c0 = sp[p + 0];
    float4 c1 = sp[p + 1];
    float4 c2 = sp[p + 2];
    float4 c3 = sp[p + 3];
    float e0 = dist_exact(qx, qy, qz, q2, c0.x, c0.y, c0.z, c0.w);
    float e1 = dist_exact(qx, qy, qz, q2, c1.x, c1.y, c1.z, c1.w);
    float e2 = dist_exact(qx, qy, qz, q2, c2.x, c2.y, c2.z, c2.w);
    float e3 = dist_exact(qx, qy, qz, q2, c3.x, c3.y, c3.z, c3.w);
    unsigned long long g0 = __ballot(e0 <= tq);
    unsigned long long g1 = __ballot(e1 <= tq);
    unsigned long long g2 = __ballot(e2 <= tq);
    unsigned long long g3 = __ballot(e3 <= tq);
    if (g0) {
      double key0 = (e0 <= tq) ? pack_key(e0, jbase + p + 0) : KINF;
      KEY_INSERT(key0);
    }
    if (g1) {
      double key1 = (e1 <= tq) ? pack_key(e1, jbase + p + 1) : KINF;
      KEY_INSERT(key1);
    }
    if (g2) {
      double key2 = (e2 <= tq) ? pack_key(e2, jbase + p + 2) : KINF;
      KEY_INSERT(key2);
    }
    if (g3) {
      double key3 = (e3 <= tq) ? pack_key(e3, jbase + p + 3) : KINF;
      KEY_INSERT(key3);
    }
  }
  double* o = &part_k[(size_t)q * (NSLICE_C * KNN) + blockIdx.y * 8];
  o[0] = k0; o[1] = k1; o[2] = k2; o[3] = k3;
  o[4] = k4; o[5] = k5; o[6] = k6; o[7] = k7;
}

// ---------------------------------------------------------------------------
// KNN D: merge 128 keys/query -> nbr (idx = low 13 bits).
// ---------------------------------------------------------------------------
__global__ __launch_bounds__(64) void knn_merge2_kernel(
    const double* __restrict__ part_k, int* __restrict__ nbr) {
  const int q = blockIdx.x * 64 + threadIdx.x;
  const double* kv = &part_k[(size_t)q * (NSLICE_C * KNN)];
  KEY_DECL;
#pragma unroll 8
  for (int u = 0; u < NSLICE_C * KNN; u += 4) {
    double a = kv[u + 0];
    double b = kv[u + 1];
    double c = kv[u + 2];
    double d = kv[u + 3];
    KEY_INSERT(a);
    KEY_INSERT(b);
    KEY_INSERT(c);
    KEY_INSERT(d);
  }
  nbr[q * KNN + 0] = __double2loint(k0) & 0x1fff;
  nbr[q * KNN + 1] = __double2loint(k1) & 0x1fff;
  nbr[q * KNN + 2] = __double2loint(k2) & 0x1fff;
  nbr[q * KNN + 3] = __double2loint(k3) & 0x1fff;
  nbr[q * KNN + 4] = __double2loint(k4) & 0x1fff;
  nbr[q * KNN + 5] = __double2loint(k5) & 0x1fff;
  nbr[q * KNN + 6] = __double2loint(k6) & 0x1fff;
  nbr[q * KNN + 7] = __double2loint(k7) & 0x1fff;
}

// ---------------------------------------------------------------------------
// Prep: Wcat (128x256) from W3; W4 split/transpose -> W4ht/W4lt[col*128+k];
// W2 (64x128) split/transpose -> W2ht/W2lt[col*64+k]. 73728 threads.
// ---------------------------------------------------------------------------
__global__ __launch_bounds__(256) void prep_kernel(
    const float* __restrict__ W3, const float* __restrict__ W4,
    const float* __restrict__ W2, float* __restrict__ Wcat,
    unsigned short* __restrict__ W4ht, unsigned short* __restrict__ W4lt,
    unsigned short* __restrict__ W2ht, unsigned short* __restrict__ W2lt) {
  const int id = blockIdx.x * 256 + threadIdx.x;
  if (id < 32768) {
    int k = id >> 8, c = id & 255;
    Wcat[id] = (c < 128) ? W3[k * 128 + c] : W3[(128 + k) * 128 + (c - 128)];
  } else if (id < 65536) {
    int i2 = id - 32768;
    int k = i2 >> 8, c = i2 & 255;
    float v = W4[k * 256 + c];
    unsigned short hi = f2bf(v);
    W4ht[c * 128 + k] = hi;
    W4lt[c * 128 + k] = f2bf(v - bf2f(hi));
  } else if (id < 73728) {
    int i2 = id - 65536;
    int k = i2 >> 7, c = i2 & 127;
    float v = W2[k * 128 + c];
    unsigned short hi = f2bf(v);
    W2ht[c * 64 + k] = hi;
    W2lt[c * 64 + k] = f2bf(v - bf2f(hi));
  }
}

// ---------------------------------------------------------------------------
// MFMA EdgeConv1 (split-bf16, gemm2 geometry): H1 = relu(e@W1+b1) computed
// fp32 in-kernel, split hi/lo bf16; W2 pre-split/transposed. K=64 in two
// panels of 32. Tile 128 edges x 128 cols, 4 waves, acc[2][8]. In-register
// segmax over each point's 8 edges + b2 + relu -> y (8192x128). grid 512.
// ---------------------------------------------------------------------------
__global__ __launch_bounds__(256) void gemm1_mfma_kernel(
    const float* __restrict__ pts, const int* __restrict__ nbr,
    const float* __restrict__ W1, const float* __restrict__ b1,
    const unsigned short* __restrict__ W2ht,
    const unsigned short* __restrict__ W2lt, const float* __restrict__ b2,
    float* __restrict__ y) {
  __shared__ float es[128][6];
  __shared__ float W1s[6][64];
  __shared__ float b1s[64];
  __shared__ unsigned short Ah[128 * 40];
  __shared__ unsigned short Al[128 * 40];
  __shared__ unsigned short Bh[128 * 40];
  __shared__ unsigned short Bl[128 * 40];
  const int t = threadIdx.x;
  const int rowBase = blockIdx.x * 128;  // edge base
  for (int idx = t; idx < 384; idx += 256) W1s[idx >> 6][idx & 63] = W1[idx];
  if (t < 64) b1s[t] = b1[t];
  if (t < 128) {
    int e = rowBase + t;
    int i = e >> 3;
    int j = nbr[e];
    float xi0 = pts[i * 3], xi1 = pts[i * 3 + 1], xi2 = pts[i * 3 + 2];
    es[t][0] = xi0;
    es[t][1] = xi1;
    es[t][2] = xi2;
    es[t][3] = pts[j * 3] - xi0;
    es[t][4] = pts[j * 3 + 1] - xi1;
    es[t][5] = pts[j * 3 + 2] - xi2;
  }
  __syncthreads();
  const int eloc = t >> 1, hh = t & 1;
  const int kb = hh * 16;
  const float f0 = es[eloc][0], f1 = es[eloc][1], f2 = es[eloc][2];
  const float f3 = es[eloc][3], f4 = es[eloc][4], f5 = es[eloc][5];
  const int lane = t & 63;
  const int w = t >> 6;
  const int q = lane >> 4;
  const int nidx = lane & 15;

  f32x4 acc[2][8];
#pragma unroll
  for (int mt = 0; mt < 2; ++mt)
#pragma unroll
    for (int nt = 0; nt < 8; ++nt) acc[mt][nt] = (f32x4){0.f, 0.f, 0.f, 0.f};

  for (int p = 0; p < 2; ++p) {
    const int k0 = p * 32;
    // ---- stage A: compute 16 H1 values fp32, split hi/lo ----
    {
      float h[16];
#pragma unroll
      for (int u4 = 0; u4 < 4; ++u4) {
        int cb = k0 + kb + u4 * 4;
        float4 w0 = *(const float4*)&W1s[0][cb];
        float4 w1 = *(const float4*)&W1s[1][cb];
        float4 w2v = *(const float4*)&W1s[2][cb];
        float4 w3 = *(const float4*)&W1s[3][cb];
        float4 w4v = *(const float4*)&W1s[4][cb];
        float4 w5 = *(const float4*)&W1s[5][cb];
        float4 bb = *(const float4*)&b1s[cb];
        const float* wp[6] = {(float*)&w0, (float*)&w1, (float*)&w2v,
                              (float*)&w3, (float*)&w4v, (float*)&w5};
        const float* bp = (const float*)&bb;
#pragma unroll
        for (int d = 0; d < 4; ++d) {
          float v = bp[d];
          v = fmaf(f0, wp[0][d], v);
          v = fmaf(f1, wp[1][d], v);
          v = fmaf(f2, wp[2][d], v);
          v = fmaf(f3, wp[3][d], v);
          v = fmaf(f4, wp[4][d], v);
          v = fmaf(f5, wp[5][d], v);
          h[u4 * 4 + d] = fmaxf(v, 0.0f);
        }
      }
      unsigned int hp[8], lp[8];
#pragma unroll
      for (int u = 0; u < 8; ++u) {
        unsigned short h0 = f2bf(h[2 * u]), h1 = f2bf(h[2 * u + 1]);
        hp[u] = (unsigned int)h0 | ((unsigned int)h1 << 16);
        unsigned short l0 = f2bf(h[2 * u] - bf2f(h0));
        unsigned short l1 = f2bf(h[2 * u + 1] - bf2f(h1));
        lp[u] = (unsigned int)l0 | ((unsigned int)l1 << 16);
      }
      *(uint4*)&Ah[eloc * 40 + kb] = make_uint4(hp[0], hp[1], hp[2], hp[3]);
      *(uint4*)&Ah[eloc * 40 + kb + 8] =
          make_uint4(hp[4], hp[5], hp[6], hp[7]);
      *(uint4*)&Al[eloc * 40 + kb] = make_uint4(lp[0], lp[1], lp[2], lp[3]);
      *(uint4*)&Al[eloc * 40 + kb + 8] =
          make_uint4(lp[4], lp[5], lp[6], lp[7]);
    }
    // ---- stage B: W2 split panels (transposed [col][k]) ----
    {
      const size_t src = (size_t)eloc * 64 + k0 + kb;
      *(uint4*)&Bh[eloc * 40 + kb] = *(const uint4*)&W2ht[src];
      *(uint4*)&Bh[eloc * 40 + kb + 8] = *(const uint4*)&W2ht[src + 8];
      *(uint4*)&Bl[eloc * 40 + kb] = *(const uint4*)&W2lt[src];
      *(uint4*)&Bl[eloc * 40 + kb + 8] = *(const uint4*)&W2lt[src + 8];
    }
    __syncthreads();
    bf16x8 ah[2], al[2];
#pragma unroll
    for (int mt = 0; mt < 2; ++mt) {
      int row = w * 32 + mt * 16 + nidx;
      ah[mt] = *(const bf16x8*)&Ah[row * 40 + q * 8];
      al[mt] = *(const bf16x8*)&Al[row * 40 + q * 8];
    }
#pragma unroll
    for (int nt = 0; nt < 8; ++nt) {
      int col = nt * 16 + nidx;
      bf16x8 bh = *(const bf16x8*)&Bh[col * 40 + q * 8];
      bf16x8 bl = *(const bf16x8*)&Bl[col * 40 + q * 8];
#pragma unroll
      for (int mt = 0; mt < 2; ++mt) {
        acc[mt][nt] = __builtin_amdgcn_mfma_f32_16x16x32_bf16(
            ah[mt], bh, acc[mt][nt], 0, 0, 0);
        acc[mt][nt] = __builtin_amdgcn_mfma_f32_16x16x32_bf16(
            ah[mt], bl, acc[mt][nt], 0, 0, 0);
        acc[mt][nt] = __builtin_amdgcn_mfma_f32_16x16x32_bf16(
            al[mt], bh, acc[mt][nt], 0, 0, 0);
      }
    }
    __syncthreads();
  }

  // epilogue: segmax over each point's 8 edges, +b2, relu -> y
#pragma unroll
  for (int mt = 0; mt < 2; ++mt) {
    const int ebase = rowBase + w * 32 + mt * 16;
    const int pt0 = ebase >> 3;
#pragma unroll
    for (int nt = 0; nt < 8; ++nt) {
      f32x4 a = acc[mt][nt];
      float m = fmaxf(fmaxf(a[0], a[1]), fmaxf(a[2], a[3]));
      float o = fmaxf(m, __shfl_xor(m, 16, 64));
      int cg = nt * 16 + nidx;
      if (q == 0) {
        y[(size_t)pt0 * 128 + cg] = fmaxf(o + b2[cg], 0.0f);
      } else if (q == 2) {
        y[(size_t)(pt0 + 1) * 128 + cg] = fmaxf(o + b2[cg], 0.0f);
      }
    }
  }
}

// ---------------------------------------------------------------------------
// AC = y @ Wcat (+b3 on cols<128). 64x64 GEMM (8192x128x256).
// ---------------------------------------------------------------------------
__global__ __launch_bounds__(256) void gemm_ac_kernel(
    const float* __restrict__ A, const float* __restrict__ B,
    const float* __restrict__ bias, float* __restrict__ out) {
  __shared__ float As[64][64];
  __shared__ float Bs[64][64];
  const int t = threadIdx.x;
  const int tx = t & 15, ty = t >> 4;
  const int rowBase = blockIdx.y * 64;
  const int colBase = blockIdx.x * 64;
  const float4* A4 = (const float4*)A;
  float acc[4][4] = {};
  const int K = 128, Nglob = 256;

  for (int k0 = 0; k0 < K; k0 += 64) {
#pragma unroll
    for (int it = 0; it < 4; ++it) {
      int idx = it * 256 + t;
      int row = idx & 63, kq = idx >> 6;
      float4 av = A4[(size_t)(rowBase + row) * (K >> 2) + (k0 >> 2) + kq];
      As[kq * 4 + 0][row] = av.x;
      As[kq * 4 + 1][row] = av.y;
      As[kq * 4 + 2][row] = av.z;
      As[kq * 4 + 3][row] = av.w;
    }
#pragma unroll
    for (int it = 0; it < 4; ++it) {
      int idx = it * 256 + t;
      int cq = idx & 15, kr = idx >> 4;
      float4 bv =
          *(const float4*)&B[(size_t)(k0 + kr) * Nglob + colBase + cq * 4];
      *(float4*)&Bs[kr][cq * 4] = bv;
    }
    __syncthreads();
#pragma unroll 8
    for (int k = 0; k < 64; ++k) {
      float4 a = *(const float4*)&As[k][ty * 4];
      float4 b = *(const float4*)&Bs[k][tx * 4];
      const float ar[4] = {a.x, a.y, a.z, a.w};
      const float br[4] = {b.x, b.y, b.z, b.w};
#pragma unroll
      for (int i = 0; i < 4; ++i)
#pragma unroll
        for (int jj = 0; jj < 4; ++jj)
          acc[i][jj] = fmaf(ar[i], br[jj], acc[i][jj]);
    }
    __syncthreads();
  }

#pragma unroll
  for (int i = 0; i < 4; ++i) {
    float4 o;
    float* oa = (float*)&o;
#pragma unroll
    for (int jj = 0; jj < 4; ++jj) {
      float v = acc[i][jj];
      int cg = colBase + tx * 4 + jj;
      if (cg < 128) v += bias[cg];
      oa[jj] = v;
    }
    *(float4*)&out[(size_t)(rowBase + ty * 4 + i) * Nglob + colBase + tx * 4] =
        o;
  }
}

// ---------------------------------------------------------------------------
// MFMA EdgeConv2 second layer (split-bf16), verified R7/R8.
// ---------------------------------------------------------------------------
__global__ __launch_bounds__(256) void gemm2_mfma_kernel(
    const float* __restrict__ AC, const int* __restrict__ nbr,
    const unsigned short* __restrict__ W4ht,
    const unsigned short* __restrict__ W4lt, const float* __restrict__ b4,
    float* __restrict__ out) {
  __shared__ unsigned short H2h[128 * 40];
  __shared__ unsigned short H2l[128 * 40];
  __shared__ unsigned short Wth[128 * 40];
  __shared__ unsigned short Wtl[128 * 40];
  const int t = threadIdx.x;
  const int rowBase = blockIdx.y * 128;
  const int colBase = blockIdx.x * 128;
  const int eloc = t >> 1, hh = t & 1;
  const int kb = hh * 16;
  const int edge = rowBase + eloc;
  const int ip = edge >> 3;
  const int jp = nbr[edge];
  const float* ai_p = AC + (size_t)ip * 256;
  const float* ci_p = ai_p + 128;
  const float* cj_p = AC + (size_t)jp * 256 + 128;
  const int lane = t & 63;
  const int w = t >> 6;
  const int q = lane >> 4;
  const int nidx = lane & 15;

  f32x4 acc[2][8];
#pragma unroll
  for (int mt = 0; mt < 2; ++mt)
#pragma unroll
    for (int nt = 0; nt < 8; ++nt) acc[mt][nt] = (f32x4){0.f, 0.f, 0.f, 0.f};

  for (int p = 0; p < 4; ++p) {
    const int k0 = p * 32;
    {
      float h2[16];
      const float4* a4 = (const float4*)(ai_p + k0 + kb);
      const float4* c4 = (const float4*)(ci_p + k0 + kb);
      const float4* d4 = (const float4*)(cj_p + k0 + kb);
#pragma unroll
      for (int u = 0; u < 4; ++u) {
        float4 a = a4[u], c = c4[u], d = d4[u];
        h2[u * 4 + 0] = fmaxf(a.x + d.x - c.x, 0.f);
        h2[u * 4 + 1] = fmaxf(a.y + d.y - c.y, 0.f);
        h2[u * 4 + 2] = fmaxf(a.z + d.z - c.z, 0.f);
        h2[u * 4 + 3] = fmaxf(a.w + d.w - c.w, 0.f);
      }
      unsigned int hp[8], lp[8];
#pragma unroll
      for (int u = 0; u < 8; ++u) {
        unsigned short h0 = f2bf(h2[2 * u]), h1 = f2bf(h2[2 * u + 1]);
        hp[u] = (unsigned int)h0 | ((unsigned int)h1 << 16);
        unsigned short l0 = f2bf(h2[2 * u] - bf2f(h0));
        unsigned short l1 = f2bf(h2[2 * u + 1] - bf2f(h1));
        lp[u] = (unsigned int)l0 | ((unsigned int)l1 << 16);
      }
      *(uint4*)&H2h[eloc * 40 + kb] = make_uint4(hp[0], hp[1], hp[2], hp[3]);
      *(uint4*)&H2h[eloc * 40 + kb + 8] =
          make_uint4(hp[4], hp[5], hp[6], hp[7]);
      *(uint4*)&H2l[eloc * 40 + kb] = make_uint4(lp[0], lp[1], lp[2], lp[3]);
      *(uint4*)&H2l[eloc * 40 + kb + 8] =
          make_uint4(lp[4], lp[5], lp[6], lp[7]);
    }
    {
      const size_t src = (size_t)(colBase + eloc) * 128 + k0 + kb;
      *(uint4*)&Wth[eloc * 40 + kb] = *(const uint4*)&W4ht[src];
      *(uint4*)&Wth[eloc * 40 + kb + 8] = *(const uint4*)&W4ht[src + 8];
      *(uint4*)&Wtl[eloc * 40 + kb] = *(const uint4*)&W4lt[src];
      *(uint4*)&Wtl[eloc * 40 + kb + 8] = *(const uint4*)&W4lt[src + 8];
    }
    __syncthreads();
    bf16x8 ah[2], al[2];
#pragma unroll
    for (int mt = 0; mt < 2; ++mt) {
      int row = w * 32 + mt * 16 + nidx;
      ah[mt] = *(const bf16x8*)&H2h[row * 40 + q * 8];
      al[mt] = *(const bf16x8*)&H2l[row * 40 + q * 8];
    }
#pragma unroll
    for (int nt = 0; nt < 8; ++nt) {
      int col = nt * 16 + nidx;
      bf16x8 bh = *(const bf16x8*)&Wth[col * 40 + q * 8];
      bf16x8 bl = *(const bf16x8*)&Wtl[col * 40 + q * 8];
#pragma unroll
      for (int mt = 0; mt < 2; ++mt) {
        acc[mt][nt] = __builtin_amdgcn_mfma_f32_16x16x32_bf16(
            ah[mt], bh, acc[mt][nt], 0, 0, 0);
        acc[mt][nt] = __builtin_amdgcn_mfma_f32_16x16x32_bf16(
            ah[mt], bl, acc[mt][nt], 0, 0, 0);
        acc[mt][nt] = __builtin_amdgcn_mfma_f32_16x16x32_bf16(
            al[mt], bh, acc[mt][nt], 0, 0, 0);
      }
    }
    __syncthreads();
  }

#pragma unroll
  for (int mt = 0; mt < 2; ++mt) {
    const int ebase = rowBase + w * 32 + mt * 16;
    const int pt0 = ebase >> 3;
#pragma unroll
    for (int nt = 0; nt < 8; ++nt) {
      f32x4 a = acc[mt][nt];
      float m = fmaxf(fmaxf(a[0], a[1]), fmaxf(a[2], a[3]));
      float o = fmaxf(m, __shfl_xor(m, 16, 64));
      int cg = colBase + nt * 16 + nidx;
      if (q == 0) {
        out[(size_t)pt0 * 256 + cg] = o + b4[cg];
      } else if (q == 2) {
        out[(size_t)(pt0 + 1) * 256 + cg] = o + b4[cg];
      }
    }
  }
}

extern "C" void kernel_launch(void* const* d_in, const int* in_sizes, int n_in,
                              void* d_out, int out_size, void* d_ws,
                              size_t ws_size, hipStream_t stream) {
  const float* pts = (const float*)d_in[0];
  const float* W1 = (const float*)d_in[1];
  const float* b1 = (const float*)d_in[2];
  const float* W2 = (const float*)d_in[3];
  const float* b2 = (const float*)d_in[4];
  const float* W3 = (const float*)d_in[5];
  const float* b3 = (const float*)d_in[6];
  const float* W4 = (const float*)d_in[7];
  const float* b4 = (const float*)d_in[8];
  float* out = (float*)d_out;

  float* w = (float*)d_ws;
  float* part_v = w;                           // 1048576 f
  float* tau = w + 1048576;                    // 8192 f
  double* part_k = (double*)(w + 1056768);     // 8192*128 dbl
  int* nbr = (int*)(w + 3153920);              // 65536 i
  float* y = w + 3219456;                      // 1048576 f
  float* Wcat = w + 4268032;                   // 32768 f
  float* AC = w + 4300800;                     // 2097152 f
  unsigned short* W4ht = (unsigned short*)(w + 6397952);  // 32768 us
  unsigned short* W4lt = (unsigned short*)(w + 6414336);  // 32768 us
  unsigned short* W2ht = (unsigned short*)(w + 6430720);  // 8192 us
  unsigned short* W2lt = (unsigned short*)(w + 6434816);  // 8192 us

  // prep is independent of KNN
  prep_kernel<<<288, 256, 0, stream>>>(W3, W4, W2, Wcat, W4ht, W4lt, W2ht,
                                       W2lt);

  // 1. KNN: subset vals -> tau (upper bound) -> ballot-gated exact capture
  knn_subset_kernel<<<dim3(32, NSLICE_A), 256, 0, stream>>>(pts, part_v);
  knn_tau_kernel<<<32, 256, 0, stream>>>(part_v, tau);
  knn_scan_tau_kernel<<<dim3(32, NSLICE_C), 256, 0, stream>>>(pts, tau,
                                                              part_k);
  knn_merge2_kernel<<<128, 64, 0, stream>>>(part_k, nbr);

  // 2. EdgeConv1 (MFMA split-bf16: H1 + GEMM + max8 + b2 + relu)
  gemm1_mfma_kernel<<<512, 256, 0, stream>>>(pts, nbr, W1, b1, W2ht, W2lt, b2,
                                             y);

  // 3. EdgeConv2: AC = y@Wcat (+b3), then MFMA H2+GEMM+max8+b4 -> out
  gemm_ac_kernel<<<dim3(4, 128), 256, 0, stream>>>(y, Wcat, b3, AC);
  gemm2_mfma_kernel<<<dim3(2, 512), 256, 0, stream>>>(AC, nbr, W4ht, W4lt, b4,
                                                      out);
}